// Round 6
// baseline (176.492 us; speedup 1.0000x reference)
//
#include <hip/hip_runtime.h>
#include <hip/hip_bf16.h>
#include <stdint.h>

#define B_DIM 32
#define I_DIM 2048
#define J_DIM 2048
#define K_DIM 128

typedef __attribute__((ext_vector_type(8))) short bf16x8;
typedef __attribute__((ext_vector_type(4))) short short4v;
typedef __attribute__((ext_vector_type(4))) float f32x4;

__device__ inline short f2bf(float f) {
  union { float f; uint32_t u; } v; v.f = f;
  uint32_t u = v.u + 0x7fffu + ((v.u >> 16) & 1u);  // RNE
  return (short)(u >> 16);
}

// ---------------- pass 1a: A fp32 [b][i][k] -> bf16 (same layout) ----------------
__global__ __launch_bounds__(256) void convA_kernel(const float* __restrict__ A,
                                                    short* __restrict__ Ab) {
  const int idx = blockIdx.x * 256 + threadIdx.x;     // 8 elements each
  const float4* p = reinterpret_cast<const float4*>(A) + (size_t)idx * 2;
  const float4 a = p[0], b = p[1];
  bf16x8 o;
  o[0] = f2bf(a.x); o[1] = f2bf(a.y); o[2] = f2bf(a.z); o[3] = f2bf(a.w);
  o[4] = f2bf(b.x); o[5] = f2bf(b.y); o[6] = f2bf(b.z); o[7] = f2bf(b.w);
  reinterpret_cast<bf16x8*>(Ab)[idx] = o;
}

// ---------------- pass 1b: B fp32 [b][k][j] -> Bt bf16 [b][j][k] ----------------
__global__ __launch_bounds__(256) void transB_kernel(const float* __restrict__ B,
                                                     short* __restrict__ Bt) {
  __shared__ __align__(16) short tile[64 * 128];
  const int t  = threadIdx.x;
  const int j0 = blockIdx.x * 64;
  const int b  = blockIdx.y;
  const float* Bb = B + (size_t)b * K_DIM * J_DIM;
  const int jj = t & 63, kq = t >> 6;
  #pragma unroll
  for (int kr = 0; kr < 32; ++kr) {
    const int k = kr * 4 + kq;
    const float v = Bb[(size_t)k * J_DIM + j0 + jj];
    tile[jj * 128 + (k ^ ((jj & 15) << 3))] = f2bf(v);
  }
  __syncthreads();
  short* Btb = Bt + (size_t)b * J_DIM * K_DIM;
  const int slot = t & 15, jr = t >> 4;
  #pragma unroll
  for (int r2 = 0; r2 < 4; ++r2) {
    const int j  = r2 * 16 + jr;
    const bf16x8 v = *reinterpret_cast<const bf16x8*>(&tile[j * 128 + slot * 8]);
    const int k0 = (slot * 8) ^ ((j & 15) << 3);
    *reinterpret_cast<bf16x8*>(Btb + (size_t)(j0 + j) * K_DIM + k0) = v;
  }
}

// ---------------- pass 2: barrier-free 1-wave GEMM, 64x64 tile ----------------
// Each block = 1 wave = one 64x64 output tile, K=128 in two 16KB single-buffered
// phases. No __syncthreads anywhere: ordering is per-wave s_waitcnt only.
// LDS strip layout: [64 r][64 k] bf16 (128B rows, 8x16B chunks); element
// (r, chunk q) stored at chunk q ^ (r&7)  (uniform 8-way = structural minimum).
#define GLD_LDS16(g, l) __builtin_amdgcn_global_load_lds( \
    (const __attribute__((address_space(1))) uint32_t*)(g), \
    (__attribute__((address_space(3))) uint32_t*)(l), 16, 0, 0)

__global__ __launch_bounds__(64, 4) void gemm_kernel(const short* __restrict__ Ab,
                                                     const short* __restrict__ Bt,
                                                     float* __restrict__ C) {
  __shared__ __align__(16) char lds[16384];   // [0,8K): A strip, [8K,16K): B strip
  const int l = threadIdx.x;                  // 0..63 (one wave)

  // XCD swizzle: 8 XCDs x 4096 blocks; each XCD owns 4 whole batches.
  const int p   = blockIdx.x;
  const int lid = ((p & 7) << 12) | (p >> 3);   // 32768 % 8 == 0 -> bijective
  const int jt  = lid & 31;
  const int it  = (lid >> 5) & 31;
  const int b   = lid >> 10;

  // staging: inst i covers LDS strip rows 8i..8i+7 (1KB, lane l -> byte 16l).
  // lane l: row sub rs=l>>3, dest chunk d=l&7 -> source chunk d ^ rs.
  const int rs = l >> 3;
  const int cs = ((l & 7) ^ rs) << 4;           // pre-swizzled source byte
  const char* Ag = (const char*)(Ab + ((size_t)b * I_DIM + it * 64 + rs) * K_DIM) + cs;
  const char* Bg = (const char*)(Bt + ((size_t)b * J_DIM + jt * 64 + rs) * K_DIM) + cs;
  // global row = 256B; phase ph adds ph*128 bytes (k-half); inst i adds i*2048.

  const int lr = l & 15, g = l >> 4;

  f32x4 acc[4][4];
  #pragma unroll
  for (int m = 0; m < 4; ++m)
    #pragma unroll
    for (int n = 0; n < 4; ++n)
      acc[m][n] = (f32x4){0.f, 0.f, 0.f, 0.f};

  // ---- stage phase 0 (k 0..63) ----
  #pragma unroll
  for (int i = 0; i < 8; ++i) {
    GLD_LDS16(Ag + i * 2048, lds + i * 1024);
    GLD_LDS16(Bg + i * 2048, lds + 8192 + i * 1024);
  }
  asm volatile("s_waitcnt vmcnt(0)" ::: "memory");
  __builtin_amdgcn_sched_barrier(0);

  #pragma unroll
  for (int ph = 0; ph < 2; ++ph) {
    // kk = 0 frags + MFMA
    bf16x8 af[4], bf[4];
    #pragma unroll
    for (int m = 0; m < 4; ++m) {
      const int R = m * 16 + lr;
      af[m] = *reinterpret_cast<const bf16x8*>(lds + R * 128 + ((g ^ (lr & 7)) << 4));
      bf[m] = *reinterpret_cast<const bf16x8*>(lds + 8192 + R * 128 + ((g ^ (lr & 7)) << 4));
    }
    #pragma unroll
    for (int m = 0; m < 4; ++m)
      #pragma unroll
      for (int n = 0; n < 4; ++n)
        acc[m][n] = __builtin_amdgcn_mfma_f32_16x16x32_bf16(af[m], bf[n], acc[m][n], 0, 0, 0);
    // kk = 1 frags
    #pragma unroll
    for (int m = 0; m < 4; ++m) {
      const int R = m * 16 + lr;
      af[m] = *reinterpret_cast<const bf16x8*>(lds + R * 128 + (((4 | g) ^ (lr & 7)) << 4));
      bf[m] = *reinterpret_cast<const bf16x8*>(lds + 8192 + R * 128 + (((4 | g) ^ (lr & 7)) << 4));
    }
    if (ph == 0) {
      // all phase-0 LDS reads must be complete before re-staging over the buffer
      asm volatile("s_waitcnt lgkmcnt(0)" ::: "memory");
      __builtin_amdgcn_sched_barrier(0);
      #pragma unroll
      for (int i = 0; i < 8; ++i) {
        GLD_LDS16(Ag + i * 2048 + 128, lds + i * 1024);          // k 64..127
        GLD_LDS16(Bg + i * 2048 + 128, lds + 8192 + i * 1024);
      }
      __builtin_amdgcn_sched_barrier(0);
    }
    #pragma unroll
    for (int m = 0; m < 4; ++m)
      #pragma unroll
      for (int n = 0; n < 4; ++n)
        acc[m][n] = __builtin_amdgcn_mfma_f32_16x16x32_bf16(af[m], bf[n], acc[m][n], 0, 0, 0);
    if (ph == 0) {
      asm volatile("s_waitcnt vmcnt(0)" ::: "memory");           // phase-1 data landed
      __builtin_amdgcn_sched_barrier(0);
    }
  }

  // ---- C write (fire-and-forget) ----
  float* Cb = C + (size_t)b * I_DIM * J_DIM;
  const int cbase = jt * 64 + lr;
  #pragma unroll
  for (int m = 0; m < 4; ++m) {
    const int rbase = it * 64 + m * 16 + g * 4;
    #pragma unroll
    for (int q = 0; q < 4; ++q) {
      float* crow = Cb + (size_t)(rbase + q) * J_DIM + cbase;
      #pragma unroll
      for (int n = 0; n < 4; ++n) crow[n * 16] = acc[m][n][q];
    }
  }
}

// ---------------- fallback (used only if ws too small) ----------------
__device__ inline int swz_fb(int row, int kbyte) {
  return row * 128 + ((kbyte ^ ((row & 15) << 4)) >> 1);
}

__global__ __launch_bounds__(256, 2) void bmm_fallback(const float* __restrict__ A,
                                                       const float* __restrict__ Bm,
                                                       float* __restrict__ C) {
  __shared__ short As[128 * 128];
  __shared__ short Bs[128 * 128];
  const int t  = threadIdx.x;
  const int jt = blockIdx.x, it = blockIdx.y, b = blockIdx.z;
  const float* Abp = A  + (size_t)b * I_DIM * K_DIM;
  const float* Bbp = Bm + (size_t)b * K_DIM * J_DIM;
  {
    const int r0 = t >> 5;
    const int k0 = (t & 31) * 4;
    #pragma unroll 4
    for (int i8 = 0; i8 < 16; ++i8) {
      const int r = i8 * 8 + r0;
      const float4 v = *reinterpret_cast<const float4*>(
          Abp + (size_t)(it * 128 + r) * K_DIM + k0);
      short4v s; s.x = f2bf(v.x); s.y = f2bf(v.y); s.z = f2bf(v.z); s.w = f2bf(v.w);
      *reinterpret_cast<short4v*>(&As[swz_fb(r, 2 * k0)]) = s;
    }
  }
  {
    const int j  = t & 127;
    const int kq = (t >> 7) * 4;
    #pragma unroll 4
    for (int kb = 0; kb < 16; ++kb) {
      const int k0 = kb * 8 + kq;
      const float* p = Bbp + (size_t)k0 * J_DIM + jt * 128 + j;
      const float f0 = p[0], f1 = p[J_DIM], f2 = p[2 * J_DIM], f3 = p[3 * J_DIM];
      short4v s; s.x = f2bf(f0); s.y = f2bf(f1); s.z = f2bf(f2); s.w = f2bf(f3);
      *reinterpret_cast<short4v*>(&Bs[swz_fb(j, 2 * k0)]) = s;
    }
  }
  __syncthreads();
  const int w = t >> 6, wm = w >> 1, wn = w & 1;
  const int lane = t & 63, lr = lane & 15, g = lane >> 4;
  f32x4 acc[4][4];
  #pragma unroll
  for (int m = 0; m < 4; ++m)
    #pragma unroll
    for (int n = 0; n < 4; ++n) acc[m][n] = (f32x4){0.f, 0.f, 0.f, 0.f};
  #pragma unroll
  for (int kk = 0; kk < 4; ++kk) {
    bf16x8 af[4], bfr[4];
    const int kb = kk * 64 + g * 16;
    #pragma unroll
    for (int m = 0; m < 4; ++m) {
      const int r = wm * 64 + m * 16 + lr;
      af[m] = *reinterpret_cast<const bf16x8*>(&As[swz_fb(r, kb)]);
    }
    #pragma unroll
    for (int n = 0; n < 4; ++n) {
      const int r = wn * 64 + n * 16 + lr;
      bfr[n] = *reinterpret_cast<const bf16x8*>(&Bs[swz_fb(r, kb)]);
    }
    #pragma unroll
    for (int m = 0; m < 4; ++m)
      #pragma unroll
      for (int n = 0; n < 4; ++n)
        acc[m][n] = __builtin_amdgcn_mfma_f32_16x16x32_bf16(af[m], bfr[n], acc[m][n], 0, 0, 0);
  }
  float* Cb = C + (size_t)b * I_DIM * J_DIM;
  const int cbase = jt * 128 + wn * 64 + lr;
  #pragma unroll
  for (int m = 0; m < 4; ++m) {
    const int rbase = it * 128 + wm * 64 + m * 16 + g * 4;
    #pragma unroll
    for (int q = 0; q < 4; ++q) {
      float* crow = Cb + (size_t)(rbase + q) * J_DIM + cbase;
      #pragma unroll
      for (int n = 0; n < 4; ++n) crow[n * 16] = acc[m][n][q];
    }
  }
}

extern "C" void kernel_launch(void* const* d_in, const int* in_sizes, int n_in,
                              void* d_out, int out_size, void* d_ws, size_t ws_size,
                              hipStream_t stream) {
  const float* A  = (const float*)d_in[0];
  const float* Bm = (const float*)d_in[1];
  float* C = (float*)d_out;
  const size_t needA = (size_t)B_DIM * I_DIM * K_DIM * sizeof(short);  // 16 MiB
  const size_t needB = (size_t)B_DIM * K_DIM * J_DIM * sizeof(short);  // 16 MiB
  if (ws_size >= needA + needB) {
    short* Ab = (short*)d_ws;
    short* Bt = (short*)((char*)d_ws + needA);
    convA_kernel<<<4096, 256, 0, stream>>>(A, Ab);
    transB_kernel<<<dim3(J_DIM / 64, B_DIM), 256, 0, stream>>>(Bm, Bt);
    gemm_kernel<<<32768, 64, 0, stream>>>(Ab, Bt, C);
  } else {
    bmm_fallback<<<dim3(J_DIM / 128, I_DIM / 128, B_DIM), 256, 0, stream>>>(A, Bm, C);
  }
}

// Round 7
// 155.171 us; speedup vs baseline: 1.1374x; 1.1374x over previous
//
#include <hip/hip_runtime.h>
#include <hip/hip_bf16.h>
#include <stdint.h>

#define B_DIM 32
#define I_DIM 2048
#define J_DIM 2048
#define K_DIM 128

typedef __attribute__((ext_vector_type(8))) short bf16x8;
typedef __attribute__((ext_vector_type(4))) short short4v;
typedef __attribute__((ext_vector_type(4))) float f32x4;

__device__ inline short f2bf(float f) {
  union { float f; uint32_t u; } v; v.f = f;
  uint32_t u = v.u + 0x7fffu + ((v.u >> 16) & 1u);  // RNE
  return (short)(u >> 16);
}

// ---------------- pass 1 (fused): A conv + B conv/transpose ----------------
// blocks [0, 4096):      A fp32 [b][i][k] -> Ab bf16 (same layout)
// blocks [4096, 5120):   B fp32 [b][k][j] -> Bt bf16 [b][j][k]
// fp32 inputs are read-once -> nontemporal loads (don't displace ws in L2).
__global__ __launch_bounds__(256) void prep_kernel(const float* __restrict__ A,
                                                   const float* __restrict__ B,
                                                   short* __restrict__ Ab,
                                                   short* __restrict__ Bt) {
  const int t = threadIdx.x;
  if (blockIdx.x < 4096) {
    const int idx = blockIdx.x * 256 + t;             // 8 elements each
    const f32x4* p = reinterpret_cast<const f32x4*>(A) + (size_t)idx * 2;
    const f32x4 a = __builtin_nontemporal_load(p);
    const f32x4 b = __builtin_nontemporal_load(p + 1);
    bf16x8 o;
    o[0] = f2bf(a.x); o[1] = f2bf(a.y); o[2] = f2bf(a.z); o[3] = f2bf(a.w);
    o[4] = f2bf(b.x); o[5] = f2bf(b.y); o[6] = f2bf(b.z); o[7] = f2bf(b.w);
    reinterpret_cast<bf16x8*>(Ab)[idx] = o;
    return;
  }
  __shared__ __align__(16) short tile[64 * 128];
  const int pb = blockIdx.x - 4096;
  const int j0 = (pb & 31) * 64;
  const int b  = pb >> 5;
  const float* Bb = B + (size_t)b * K_DIM * J_DIM;
  const int jj = t & 63, kq = t >> 6;
  #pragma unroll
  for (int kr = 0; kr < 32; ++kr) {
    const int k = kr * 4 + kq;
    const float v = __builtin_nontemporal_load(&Bb[(size_t)k * J_DIM + j0 + jj]);
    tile[jj * 128 + (k ^ ((jj & 15) << 3))] = f2bf(v);
  }
  __syncthreads();
  short* Btb = Bt + (size_t)b * J_DIM * K_DIM;
  const int slot = t & 15, jr = t >> 4;
  #pragma unroll
  for (int r2 = 0; r2 < 4; ++r2) {
    const int j  = r2 * 16 + jr;
    const bf16x8 v = *reinterpret_cast<const bf16x8*>(&tile[j * 128 + slot * 8]);
    const int k0 = (slot * 8) ^ ((j & 15) << 3);
    *reinterpret_cast<bf16x8*>(Btb + (size_t)(j0 + j) * K_DIM + k0) = v;
  }
}

// ---------------- pass 2: bf16 GEMM, 128x128 tile, BK=64, global_load_lds ----------------
// R3/R5 structure; single change: C stores are NONTEMPORAL (bypass/deprioritize
// L2 so the 512MB C stream stops evicting the 32MB ws working set).
#define GLD_LDS16(g, l) __builtin_amdgcn_global_load_lds( \
    (const __attribute__((address_space(1))) uint32_t*)(g), \
    (__attribute__((address_space(3))) uint32_t*)(l), 16, 0, 0)

__global__ __launch_bounds__(256, 4) void gemm_kernel(const short* __restrict__ Ab,
                                                      const short* __restrict__ Bt,
                                                      float* __restrict__ C) {
  __shared__ __align__(16) short As[8192];   // [128 r][64 k] bf16, swizzled
  __shared__ __align__(16) short Bs[8192];
  const int t = threadIdx.x;

  // XCD swizzle (bijective, 8192 % 8 == 0): each XCD owns 4 whole batches.
  const int p   = blockIdx.x;
  const int lid = ((p & 7) << 10) | (p >> 3);
  const int jt  = lid & 15;
  const int it  = (lid >> 4) & 15;
  const int b   = lid >> 8;

  const int rsub  = t >> 3;                                   // 0..31
  const int kbyte = ((t & 7) << 4) ^ ((rsub & 7) << 4);       // pre-swizzled source
  const char* Asrc = (const char*)(Ab + (size_t)(b * I_DIM + it * 128 + rsub) * K_DIM) + kbyte;
  const char* Bsrc = (const char*)(Bt + (size_t)(b * J_DIM + jt * 128 + rsub) * K_DIM) + kbyte;
  char* Adst = (char*)As + (t >> 6) * 1024;   // wave-uniform base; HW adds lane*16
  char* Bdst = (char*)Bs + (t >> 6) * 1024;

  const int w = t >> 6, wm = w >> 1, wn = w & 1;
  const int lane = t & 63, lr = lane & 15, g = lane >> 4;
  const int swr = (lr & 7) << 4;              // read-side XOR

  f32x4 acc[4][4];
  #pragma unroll
  for (int m = 0; m < 4; ++m)
    #pragma unroll
    for (int n = 0; n < 4; ++n)
      acc[m][n] = (f32x4){0.f, 0.f, 0.f, 0.f};

  #pragma unroll
  for (int ki = 0; ki < 2; ++ki) {            // K = 2 x BK=64
    if (ki) __syncthreads();                  // drain reads before overwriting LDS
    #pragma unroll
    for (int q = 0; q < 4; ++q) {
      GLD_LDS16(Asrc + q * 8192 + ki * 128, Adst + q * 4096);
      GLD_LDS16(Bsrc + q * 8192 + ki * 128, Bdst + q * 4096);
    }
    __syncthreads();
    #pragma unroll
    for (int kk = 0; kk < 2; ++kk) {
      bf16x8 af[4], bb[4];
      const int cb = kk * 64 + g * 16;
      #pragma unroll
      for (int m = 0; m < 4; ++m) {
        const int R = wm * 64 + m * 16 + lr;
        af[m] = *reinterpret_cast<const bf16x8*>((const char*)As + R * 128 + (cb ^ swr));
      }
      #pragma unroll
      for (int n = 0; n < 4; ++n) {
        const int R = wn * 64 + n * 16 + lr;
        bb[n] = *reinterpret_cast<const bf16x8*>((const char*)Bs + R * 128 + (cb ^ swr));
      }
      #pragma unroll
      for (int m = 0; m < 4; ++m)
        #pragma unroll
        for (int n = 0; n < 4; ++n)
          acc[m][n] = __builtin_amdgcn_mfma_f32_16x16x32_bf16(af[m], bb[n], acc[m][n], 0, 0, 0);
    }
  }

  // C write: col = lane&15, row = g*4 + reg — NONTEMPORAL stores
  float* Cb = C + (size_t)b * I_DIM * J_DIM;
  const int cbase = jt * 128 + wn * 64 + lr;
  #pragma unroll
  for (int m = 0; m < 4; ++m) {
    const int rbase = it * 128 + wm * 64 + m * 16 + g * 4;
    #pragma unroll
    for (int q = 0; q < 4; ++q) {
      float* crow = Cb + (size_t)(rbase + q) * J_DIM + cbase;
      #pragma unroll
      for (int n = 0; n < 4; ++n)
        __builtin_nontemporal_store(acc[m][n][q], crow + n * 16);
    }
  }
}

// ---------------- fallback (used only if ws too small) ----------------
__device__ inline int swz_fb(int row, int kbyte) {
  return row * 128 + ((kbyte ^ ((row & 15) << 4)) >> 1);
}

__global__ __launch_bounds__(256, 2) void bmm_fallback(const float* __restrict__ A,
                                                       const float* __restrict__ Bm,
                                                       float* __restrict__ C) {
  __shared__ short As[128 * 128];
  __shared__ short Bs[128 * 128];
  const int t  = threadIdx.x;
  const int jt = blockIdx.x, it = blockIdx.y, b = blockIdx.z;
  const float* Abp = A  + (size_t)b * I_DIM * K_DIM;
  const float* Bbp = Bm + (size_t)b * K_DIM * J_DIM;
  {
    const int r0 = t >> 5;
    const int k0 = (t & 31) * 4;
    #pragma unroll 4
    for (int i8 = 0; i8 < 16; ++i8) {
      const int r = i8 * 8 + r0;
      const float4 v = *reinterpret_cast<const float4*>(
          Abp + (size_t)(it * 128 + r) * K_DIM + k0);
      short4v s; s.x = f2bf(v.x); s.y = f2bf(v.y); s.z = f2bf(v.z); s.w = f2bf(v.w);
      *reinterpret_cast<short4v*>(&As[swz_fb(r, 2 * k0)]) = s;
    }
  }
  {
    const int j  = t & 127;
    const int kq = (t >> 7) * 4;
    #pragma unroll 4
    for (int kb = 0; kb < 16; ++kb) {
      const int k0 = kb * 8 + kq;
      const float* p = Bbp + (size_t)k0 * J_DIM + jt * 128 + j;
      const float f0 = p[0], f1 = p[J_DIM], f2 = p[2 * J_DIM], f3 = p[3 * J_DIM];
      short4v s; s.x = f2bf(f0); s.y = f2bf(f1); s.z = f2bf(f2); s.w = f2bf(f3);
      *reinterpret_cast<short4v*>(&Bs[swz_fb(j, 2 * k0)]) = s;
    }
  }
  __syncthreads();
  const int w = t >> 6, wm = w >> 1, wn = w & 1;
  const int lane = t & 63, lr = lane & 15, g = lane >> 4;
  f32x4 acc[4][4];
  #pragma unroll
  for (int m = 0; m < 4; ++m)
    #pragma unroll
    for (int n = 0; n < 4; ++n) acc[m][n] = (f32x4){0.f, 0.f, 0.f, 0.f};
  #pragma unroll
  for (int kk = 0; kk < 4; ++kk) {
    bf16x8 af[4], bfr[4];
    const int kb = kk * 64 + g * 16;
    #pragma unroll
    for (int m = 0; m < 4; ++m) {
      const int r = wm * 64 + m * 16 + lr;
      af[m] = *reinterpret_cast<const bf16x8*>(&As[swz_fb(r, kb)]);
    }
    #pragma unroll
    for (int n = 0; n < 4; ++n) {
      const int r = wn * 64 + n * 16 + lr;
      bfr[n] = *reinterpret_cast<const bf16x8*>(&Bs[swz_fb(r, kb)]);
    }
    #pragma unroll
    for (int m = 0; m < 4; ++m)
      #pragma unroll
      for (int n = 0; n < 4; ++n)
        acc[m][n] = __builtin_amdgcn_mfma_f32_16x16x32_bf16(af[m], bfr[n], acc[m][n], 0, 0, 0);
  }
  float* Cb = C + (size_t)b * I_DIM * J_DIM;
  const int cbase = jt * 128 + wn * 64 + lr;
  #pragma unroll
  for (int m = 0; m < 4; ++m) {
    const int rbase = it * 128 + wm * 64 + m * 16 + g * 4;
    #pragma unroll
    for (int q = 0; q < 4; ++q) {
      float* crow = Cb + (size_t)(rbase + q) * J_DIM + cbase;
      #pragma unroll
      for (int n = 0; n < 4; ++n) crow[n * 16] = acc[m][n][q];
    }
  }
}

extern "C" void kernel_launch(void* const* d_in, const int* in_sizes, int n_in,
                              void* d_out, int out_size, void* d_ws, size_t ws_size,
                              hipStream_t stream) {
  const float* A  = (const float*)d_in[0];
  const float* Bm = (const float*)d_in[1];
  float* C = (float*)d_out;
  const size_t needA = (size_t)B_DIM * I_DIM * K_DIM * sizeof(short);  // 16 MiB
  const size_t needB = (size_t)B_DIM * K_DIM * J_DIM * sizeof(short);  // 16 MiB
  if (ws_size >= needA + needB) {
    short* Ab = (short*)d_ws;
    short* Bt = (short*)((char*)d_ws + needA);
    prep_kernel<<<5120, 256, 0, stream>>>(A, Bm, Ab, Bt);
    gemm_kernel<<<8192, 256, 0, stream>>>(Ab, Bt, C);
  } else {
    bmm_fallback<<<dim3(J_DIM / 128, I_DIM / 128, B_DIM), 256, 0, stream>>>(A, Bm, C);
  }
}